// Round 7
// baseline (209.100 us; speedup 1.0000x reference)
//
#include <hip/hip_runtime.h>

typedef __attribute__((ext_vector_type(8))) __bf16 bf16x8;
typedef __attribute__((ext_vector_type(4))) float f32x4;
typedef _Float16 f16x4 __attribute__((ext_vector_type(4)));
typedef unsigned int uint32;

#define HW   4096
#define CCH  64
#define DQ   32
#define OC   32
#define LOG2E 1.4426950408889634f

// Workspace layout (float offsets). Total ~32.5 MB.
#define WSV_OFF  0u                       // 32*64 f32
#define QB_OFF   2048u                    // bf16 [b][n][32] (pre-scaled log2e)
#define KB_OFF   (QB_OFF + 524288u)       // bf16 [b][m][32]
#define XS_OFF   (KB_OFF + 524288u)       // f32  [b][o][n]
#define V2_OFF   (XS_OFF + 1048576u)      // f32  [b][o][m]
#define ZP_OFF   (V2_OFF + 1048576u)      // f32  [8][b][m] partial Z
#define VZB_OFF  (ZP_OFF + 262144u)       // f16  [b][o][m]
#define OUTP_OFF (VZB_OFF + 524288u)      // bf16 [8][b][o][n] partial out

__device__ __forceinline__ uint32 f2bf(float x) {   // RNE
    uint32 u = __builtin_bit_cast(uint32, x);
    return (u + 0x7fffu + ((u >> 16) & 1u)) >> 16;
}
__device__ __forceinline__ uint32 packbf(float a, float b) {
    return f2bf(a) | (f2bf(b) << 16);
}
__device__ __forceinline__ bf16x8 ldfrag(const unsigned short* p) {
    union { uint4 u; bf16x8 f; } t;
    t.u = *(const uint4*)p;
    return t.f;
}
__device__ __forceinline__ f16x4 ldv4h(const unsigned short* p) {
    union { uint2 u; f16x4 f; } t;
    t.u = *(const uint2*)p;
    return t.f;
}
// pack 4 floats -> f16x4 via two v_cvt_pkrtz_f16_f32 (RTZ)
__device__ __forceinline__ f16x4 pk4(float a, float b, float c, float d) {
    union { uint2 u; f16x4 f; } t;
    t.u.x = __builtin_bit_cast(uint32, __builtin_amdgcn_cvt_pkrtz(a, b));
    t.u.y = __builtin_bit_cast(uint32, __builtin_amdgcn_cvt_pkrtz(c, d));
    return t.f;
}
__device__ __forceinline__ float fexp2(float x) {
#if __has_builtin(__builtin_amdgcn_exp2f)
    return __builtin_amdgcn_exp2f(x);
#else
    return __expf(x * 0.6931471805599453f);
#endif
}

// ---------------------------------------------------------------------------
// Kernel 0: Wsv = Wsc @ Wv
__global__ __launch_bounds__(256) void k_wcomb(const float* __restrict__ Wsc,
                                               const float* __restrict__ Wv,
                                               float* __restrict__ Wsv) {
    int t = blockIdx.x * 256 + threadIdx.x;
    if (t < OC * CCH) {
        int o = t / CCH, ci = t % CCH;
        float s = 0.f;
        #pragma unroll
        for (int c = 0; c < CCH; ++c) s += Wsc[o * CCH + c] * Wv[c * CCH + ci];
        Wsv[t] = s;
    }
}

// ---------------------------------------------------------------------------
// Kernel 1: projections. W wave-uniform scalar loads. 512 blocks x 256;
// block = 64 pixels; wave g: 0=q,1=k,2=v2,3=xs. Each lane writes FULL 64B
// q/k rows (one 64B line per pixel-row — no cross-block/XCD false sharing).
__global__ __launch_bounds__(256) void k_proj(
    const float* __restrict__ x1, const float* __restrict__ x2,
    const float* __restrict__ Wq, const float* __restrict__ bq,
    const float* __restrict__ Wk, const float* __restrict__ bk,
    const float* __restrict__ Wsv, const float* __restrict__ Wsc,
    unsigned short* __restrict__ qb, unsigned short* __restrict__ kb,
    float* __restrict__ v2, float* __restrict__ xs) {
    int t = threadIdx.x;
    int g = __builtin_amdgcn_readfirstlane(t >> 6);   // wave-uniform
    int l = t & 63;
    int p = blockIdx.x * 64 + l;
    int b = p >> 12, n = p & 4095;
    const float* x1b = x1 + (size_t)b * 32 * HW + n;
    const float* x2b = x2 + (size_t)b * 32 * HW + n;
    float x[CCH];
    #pragma unroll
    for (int c = 0; c < 32; ++c) x[c] = x1b[(size_t)c * HW];
    #pragma unroll
    for (int c = 0; c < 32; ++c) x[32 + c] = x2b[(size_t)c * HW];

    if (g < 2) {
        const float* W    = g ? Wk : Wq;
        const float* bias = g ? bk : bq;
        float scale = g ? 1.0f : LOG2E;
        unsigned short* dst = g ? kb : qb;
        size_t row = ((size_t)b * HW + n) * DQ;
        for (int d0 = 0; d0 < DQ; d0 += 8) {
            float r[8];
            #pragma unroll
            for (int i = 0; i < 8; ++i) {
                const float* wr = W + (d0 + i) * CCH;
                float a = bias[d0 + i];
                #pragma unroll
                for (int c = 0; c < CCH; ++c) a += wr[c] * x[c];
                r[i] = a * scale;
            }
            uint4 u;
            u.x = packbf(r[0], r[1]); u.y = packbf(r[2], r[3]);
            u.z = packbf(r[4], r[5]); u.w = packbf(r[6], r[7]);
            *(uint4*)(dst + row + d0) = u;
        }
    } else {
        const float* W = (g == 2) ? Wsv : Wsc;
        float* dst     = (g == 2) ? v2  : xs;
        for (int o = 0; o < OC; ++o) {
            const float* wr = W + o * CCH;
            float a = 0.f;
            #pragma unroll
            for (int c = 0; c < CCH; ++c) a += wr[c] * x[c];
            dst[((size_t)b * OC + o) * HW + n] = a;
        }
    }
}

// ---------------------------------------------------------------------------
// Kernel 2: partial Zp[nc][b][m] over 512-n chunks.
__global__ __launch_bounds__(256, 8) void k_stats(
    const unsigned short* __restrict__ kb, const unsigned short* __restrict__ qb,
    float* __restrict__ zp) {
    int t = threadIdx.x;
    int w = t >> 6, l = t & 63;
    int lr = l & 15, lq = l >> 4;
    int bid = blockIdx.x;
    int b = bid & 7, nc = (bid >> 3) & 7, mg = bid >> 6;   // mg 0..31
    int m0 = mg * 128 + w * 32;

    const unsigned short* kbb = kb + ((size_t)b * HW) * DQ;
    bf16x8 af0 = ldfrag(kbb + (size_t)(m0 + lr) * DQ + lq * 8);
    bf16x8 af1 = ldfrag(kbb + (size_t)(m0 + 16 + lr) * DQ + lq * 8);
    const unsigned short* qp = qb + ((size_t)b * HW + nc * 512 + lr) * DQ + lq * 8;

    f32x4 acc0 = {0.f, 0.f, 0.f, 0.f};
    f32x4 acc1 = {0.f, 0.f, 0.f, 0.f};
    f32x4 zz = {0.f, 0.f, 0.f, 0.f};
    #pragma unroll 4
    for (int i = 0; i < 32; ++i) {
        bf16x8 qf = ldfrag(qp);
        qp += 16 * DQ;
        f32x4 s0 = __builtin_amdgcn_mfma_f32_16x16x32_bf16(af0, qf, zz, 0, 0, 0);
        f32x4 s1 = __builtin_amdgcn_mfma_f32_16x16x32_bf16(af1, qf, zz, 0, 0, 0);
        acc0.x += fexp2(s0.x); acc0.y += fexp2(s0.y);
        acc0.z += fexp2(s0.z); acc0.w += fexp2(s0.w);
        acc1.x += fexp2(s1.x); acc1.y += fexp2(s1.y);
        acc1.z += fexp2(s1.z); acc1.w += fexp2(s1.w);
    }
    #pragma unroll
    for (int off = 1; off < 16; off <<= 1) {
        acc0.x += __shfl_xor(acc0.x, off); acc0.y += __shfl_xor(acc0.y, off);
        acc0.z += __shfl_xor(acc0.z, off); acc0.w += __shfl_xor(acc0.w, off);
        acc1.x += __shfl_xor(acc1.x, off); acc1.y += __shfl_xor(acc1.y, off);
        acc1.z += __shfl_xor(acc1.z, off); acc1.w += __shfl_xor(acc1.w, off);
    }
    if (lr == 0) {
        size_t base = (size_t)nc * 32768 + (size_t)b * HW;
        zp[base + m0 + lq * 4 + 0] = acc0.x;
        zp[base + m0 + lq * 4 + 1] = acc0.y;
        zp[base + m0 + lq * 4 + 2] = acc0.z;
        zp[base + m0 + lq * 4 + 3] = acc0.w;
        zp[base + m0 + 16 + lq * 4 + 0] = acc1.x;
        zp[base + m0 + 16 + lq * 4 + 1] = acc1.y;
        zp[base + m0 + 16 + lq * 4 + 2] = acc1.z;
        zp[base + m0 + 16 + lq * 4 + 3] = acc1.w;
    }
}

// ---------------------------------------------------------------------------
// Kernel 3 (fused scale+vz): zs = gamma/sum(zp); vzb[b][o][m] = f16(v2*zs)
__global__ __launch_bounds__(256) void k_zvz(const float* __restrict__ zp,
                                             const float* __restrict__ v2,
                                             const float* __restrict__ gamma,
                                             unsigned short* __restrict__ vzb) {
    int i = blockIdx.x * 256 + threadIdx.x;   // 32768 = [b][m]
    float s = 0.f;
    #pragma unroll
    for (int nc = 0; nc < 8; ++nc) s += zp[nc * 32768 + i];
    float zs = gamma[0] / s;
    int b = i >> 12, m = i & 4095;
    const float* vsrc = v2 + ((size_t)b * OC) * HW + m;
    unsigned short* dst = vzb + ((size_t)b * OC) * HW + m;
    #pragma unroll 8
    for (int o = 0; o < OC; ++o) {
        _Float16 h = (_Float16)(vsrc[(size_t)o * HW] * zs);
        dst[(size_t)o * HW] = __builtin_bit_cast(unsigned short, h);
    }
}

// ---------------------------------------------------------------------------
// Kernel 4: partial outp[mc][b][o][n] (bf16) = sum_{m chunk} vz*exp2(q.k)
// LDS-FREE: S C-layout (col=n, row=4*lq+r=m) IS the B-operand layout of
// mfma_f32_16x16x16f16 (k = 4*lq + j = m). P feeds PV directly in registers.
// grid = 2048: b = bid&7 (XCD-pinned), mc = (bid>>3)&7, ng = bid>>6 (0..31).
__global__ __launch_bounds__(256, 8) void k_attn(
    const unsigned short* __restrict__ qb, const unsigned short* __restrict__ kb,
    const unsigned short* __restrict__ vzb, unsigned short* __restrict__ outp) {
    int t = threadIdx.x;
    int w = t >> 6, l = t & 63;
    int lr = l & 15, lq = l >> 4;
    int bid = blockIdx.x;
    int b = bid & 7, mc = (bid >> 3) & 7, ng = bid >> 6;
    int nA = ng * 128 + w * 32;

    bf16x8 qfA = ldfrag(qb + ((size_t)b * HW + nA + lr) * DQ + lq * 8);
    bf16x8 qfB = ldfrag(qb + ((size_t)b * HW + nA + 16 + lr) * DQ + lq * 8);
    const unsigned short* kp = kb + ((size_t)b * HW + lr) * DQ + lq * 8;
    const unsigned short* vp = vzb + ((size_t)b * OC + lr) * HW + lq * 4;

    f32x4 accA0 = {0.f,0.f,0.f,0.f}, accA1 = {0.f,0.f,0.f,0.f};
    f32x4 accB0 = {0.f,0.f,0.f,0.f}, accB1 = {0.f,0.f,0.f,0.f};
    f32x4 zz = {0.f,0.f,0.f,0.f};

    int mbeg = mc * 512;
    for (int m0 = mbeg; m0 < mbeg + 512; m0 += 32) {
        #pragma unroll
        for (int ph = 0; ph < 2; ++ph) {
            int mb = m0 + ph * 16;
            // k-frag: A[m=lr][d=8*lq+j] for S; v-frags: A[o=lr][m=4*lq+j] for PV
            bf16x8 a   = ldfrag(kp + (size_t)mb * DQ);
            f16x4  va0 = ldv4h(vp + mb);
            f16x4  va1 = ldv4h(vp + (size_t)16 * HW + mb);
            f32x4 sA = __builtin_amdgcn_mfma_f32_16x16x32_bf16(a, qfA, zz, 0, 0, 0);
            f32x4 sB = __builtin_amdgcn_mfma_f32_16x16x32_bf16(a, qfB, zz, 0, 0, 0);
            f16x4 pA = pk4(fexp2(sA.x), fexp2(sA.y), fexp2(sA.z), fexp2(sA.w));
            f16x4 pB = pk4(fexp2(sB.x), fexp2(sB.y), fexp2(sB.z), fexp2(sB.w));
            accA0 = __builtin_amdgcn_mfma_f32_16x16x16f16(va0, pA, accA0, 0, 0, 0);
            accA1 = __builtin_amdgcn_mfma_f32_16x16x16f16(va1, pA, accA1, 0, 0, 0);
            accB0 = __builtin_amdgcn_mfma_f32_16x16x16f16(va0, pB, accB0, 0, 0, 0);
            accB1 = __builtin_amdgcn_mfma_f32_16x16x16f16(va1, pB, accB1, 0, 0, 0);
        }
    }

    // bf16 partial write: C layout col=lr=n, row=lq*4+r=o
    // (each wave writes full 64B lines; blocks disjoint at 256B granularity)
    int n_A = nA + lr, n_B = nA + 16 + lr;
    unsigned short* ob = outp + ((size_t)(mc * 8 + b) * OC) * HW;
    #pragma unroll
    for (int r = 0; r < 4; ++r) {
        int o0 = lq * 4 + r;
        ob[(size_t)o0 * HW + n_A]        = (unsigned short)f2bf(accA0[r]);
        ob[(size_t)(o0 + 16) * HW + n_A] = (unsigned short)f2bf(accA1[r]);
        ob[(size_t)o0 * HW + n_B]        = (unsigned short)f2bf(accB0[r]);
        ob[(size_t)(o0 + 16) * HW + n_B] = (unsigned short)f2bf(accB1[r]);
    }
}

// ---------------------------------------------------------------------------
// Kernel 5: out = sum_mc bf16 outp[mc] + xs
__global__ __launch_bounds__(256) void k_red(const unsigned short* __restrict__ outp,
                                             const float* __restrict__ xs,
                                             float* __restrict__ out) {
    int i = (blockIdx.x * 256 + threadIdx.x) * 4;
    float4 r = *(const float4*)(xs + i);
    const unsigned short* op = outp + i;
    #pragma unroll
    for (int mc = 0; mc < 8; ++mc) {
        uint2 p = *(const uint2*)(op + (size_t)mc * 1048576);
        r.x += __builtin_bit_cast(float, p.x << 16);
        r.y += __builtin_bit_cast(float, p.x & 0xffff0000u);
        r.z += __builtin_bit_cast(float, p.y << 16);
        r.w += __builtin_bit_cast(float, p.y & 0xffff0000u);
    }
    *(float4*)(out + i) = r;
}

// ---------------------------------------------------------------------------
extern "C" void kernel_launch(void* const* d_in, const int* in_sizes, int n_in,
                              void* d_out, int out_size, void* d_ws, size_t ws_size,
                              hipStream_t stream) {
    const float* x1    = (const float*)d_in[0];
    const float* x2    = (const float*)d_in[1];
    const float* Wq    = (const float*)d_in[2];
    const float* bq    = (const float*)d_in[3];
    const float* Wk    = (const float*)d_in[4];
    const float* bk    = (const float*)d_in[5];
    const float* Wv    = (const float*)d_in[6];
    const float* Wsc   = (const float*)d_in[7];
    const float* gamma = (const float*)d_in[8];
    float* out = (float*)d_out;
    float* ws  = (float*)d_ws;

    float*          wsv  = ws + WSV_OFF;
    unsigned short* qbp  = (unsigned short*)(ws + QB_OFF);
    unsigned short* kbp  = (unsigned short*)(ws + KB_OFF);
    float*          xsp  = ws + XS_OFF;
    float*          v2   = ws + V2_OFF;
    float*          zpp  = ws + ZP_OFF;
    unsigned short* vzb  = (unsigned short*)(ws + VZB_OFF);
    unsigned short* outp = (unsigned short*)(ws + OUTP_OFF);

    k_wcomb<<<8, 256, 0, stream>>>(Wsc, Wv, wsv);
    k_proj<<<512, 256, 0, stream>>>(x1, x2, Wq, bq, Wk, bk, wsv, Wsc,
                                    qbp, kbp, v2, xsp);
    k_stats<<<2048, 256, 0, stream>>>(kbp, qbp, zpp);
    k_zvz<<<128, 256, 0, stream>>>(zpp, v2, gamma, vzb);
    k_attn<<<2048, 256, 0, stream>>>(qbp, kbp, vzb, outp);
    k_red<<<1024, 256, 0, stream>>>(outp, xsp, out);
}

// Round 8
// 167.116 us; speedup vs baseline: 1.2512x; 1.2512x over previous
//
#include <hip/hip_runtime.h>

typedef __attribute__((ext_vector_type(8))) __bf16 bf16x8;
typedef __attribute__((ext_vector_type(4))) float f32x4;
typedef _Float16 f16x4 __attribute__((ext_vector_type(4)));
typedef unsigned int uint32;

#define HW   4096
#define CCH  64
#define DQ   32
#define OC   32
#define LOG2E 1.4426950408889634f

// Workspace layout (float offsets). Total ~32.5 MB.
#define WSV_OFF  0u                       // 32*64 f32
#define QB_OFF   2048u                    // bf16 [b][n][32] (pre-scaled log2e)
#define KB_OFF   (QB_OFF + 524288u)       // bf16 [b][m][32]
#define XS_OFF   (KB_OFF + 524288u)       // f32  [b][o][n]
#define V2_OFF   (XS_OFF + 1048576u)      // f32  [b][o][m]
#define ZP_OFF   (V2_OFF + 1048576u)      // f32  [8][b][m] partial Z
#define VZC_OFF  (ZP_OFF + 262144u)       // f16  [b][Mb][o][lq][ph][j] shuffled
#define OUTP_OFF (VZC_OFF + 524288u)      // bf16 [8][b][o][n] partial out

__device__ __forceinline__ uint32 f2bf(float x) {   // RNE
    uint32 u = __builtin_bit_cast(uint32, x);
    return (u + 0x7fffu + ((u >> 16) & 1u)) >> 16;
}
__device__ __forceinline__ uint32 packbf(float a, float b) {
    return f2bf(a) | (f2bf(b) << 16);
}
__device__ __forceinline__ bf16x8 ldfrag(const unsigned short* p) {
    union { uint4 u; bf16x8 f; } t;
    t.u = *(const uint4*)p;
    return t.f;
}
__device__ __forceinline__ f16x4 u2h4(uint32 a, uint32 b) {
    union { uint2 u; f16x4 f; } t;
    t.u.x = a; t.u.y = b;
    return t.f;
}
// pack 4 floats -> f16x4 via two v_cvt_pkrtz_f16_f32 (RTZ)
__device__ __forceinline__ f16x4 pk4(float a, float b, float c, float d) {
    union { uint2 u; f16x4 f; } t;
    t.u.x = __builtin_bit_cast(uint32, __builtin_amdgcn_cvt_pkrtz(a, b));
    t.u.y = __builtin_bit_cast(uint32, __builtin_amdgcn_cvt_pkrtz(c, d));
    return t.f;
}
__device__ __forceinline__ float fexp2(float x) {
#if __has_builtin(__builtin_amdgcn_exp2f)
    return __builtin_amdgcn_exp2f(x);
#else
    return __expf(x * 0.6931471805599453f);
#endif
}

// ---------------------------------------------------------------------------
// Kernel 0: Wsv = Wsc @ Wv
__global__ __launch_bounds__(256) void k_wcomb(const float* __restrict__ Wsc,
                                               const float* __restrict__ Wv,
                                               float* __restrict__ Wsv) {
    int t = blockIdx.x * 256 + threadIdx.x;
    if (t < OC * CCH) {
        int o = t / CCH, ci = t % CCH;
        float s = 0.f;
        #pragma unroll
        for (int c = 0; c < CCH; ++c) s += Wsc[o * CCH + c] * Wv[c * CCH + ci];
        Wsv[t] = s;
    }
}

// ---------------------------------------------------------------------------
// Kernel 1: projections (unchanged from round 7 — proven safe).
__global__ __launch_bounds__(256) void k_proj(
    const float* __restrict__ x1, const float* __restrict__ x2,
    const float* __restrict__ Wq, const float* __restrict__ bq,
    const float* __restrict__ Wk, const float* __restrict__ bk,
    const float* __restrict__ Wsv, const float* __restrict__ Wsc,
    unsigned short* __restrict__ qb, unsigned short* __restrict__ kb,
    float* __restrict__ v2, float* __restrict__ xs) {
    int t = threadIdx.x;
    int g = __builtin_amdgcn_readfirstlane(t >> 6);   // wave-uniform
    int l = t & 63;
    int p = blockIdx.x * 64 + l;
    int b = p >> 12, n = p & 4095;
    const float* x1b = x1 + (size_t)b * 32 * HW + n;
    const float* x2b = x2 + (size_t)b * 32 * HW + n;
    float x[CCH];
    #pragma unroll
    for (int c = 0; c < 32; ++c) x[c] = x1b[(size_t)c * HW];
    #pragma unroll
    for (int c = 0; c < 32; ++c) x[32 + c] = x2b[(size_t)c * HW];

    if (g < 2) {
        const float* W    = g ? Wk : Wq;
        const float* bias = g ? bk : bq;
        float scale = g ? 1.0f : LOG2E;
        unsigned short* dst = g ? kb : qb;
        size_t row = ((size_t)b * HW + n) * DQ;
        for (int d0 = 0; d0 < DQ; d0 += 8) {
            float r[8];
            #pragma unroll
            for (int i = 0; i < 8; ++i) {
                const float* wr = W + (d0 + i) * CCH;
                float a = bias[d0 + i];
                #pragma unroll
                for (int c = 0; c < CCH; ++c) a += wr[c] * x[c];
                r[i] = a * scale;
            }
            uint4 u;
            u.x = packbf(r[0], r[1]); u.y = packbf(r[2], r[3]);
            u.z = packbf(r[4], r[5]); u.w = packbf(r[6], r[7]);
            *(uint4*)(dst + row + d0) = u;
        }
    } else {
        const float* W = (g == 2) ? Wsv : Wsc;
        float* dst     = (g == 2) ? v2  : xs;
        for (int o = 0; o < OC; ++o) {
            const float* wr = W + o * CCH;
            float a = 0.f;
            #pragma unroll
            for (int c = 0; c < CCH; ++c) a += wr[c] * x[c];
            dst[((size_t)b * OC + o) * HW + n] = a;
        }
    }
}

// ---------------------------------------------------------------------------
// Kernel 2: partial Zp[nc][b][m]. Wave owns 128 m (8 resident k-frags),
// sweeps a 512-n chunk: q-line reads amortized 8x vs round 7.
// grid = 1024 x 128 thr: b=bid&7, nc=(bid>>3)&7, mg=bid>>6 (0..15).
__global__ __launch_bounds__(128, 4) void k_stats(
    const unsigned short* __restrict__ kb, const unsigned short* __restrict__ qb,
    float* __restrict__ zp) {
    int t = threadIdx.x;
    int w = t >> 6, l = t & 63;
    int lr = l & 15, lq = l >> 4;
    int bid = blockIdx.x;
    int b = bid & 7, nc = (bid >> 3) & 7, mg = bid >> 6;
    int m0 = mg * 256 + w * 128;

    const unsigned short* kbb = kb + (size_t)b * HW * DQ;
    bf16x8 af[8];
    #pragma unroll
    for (int f = 0; f < 8; ++f)
        af[f] = ldfrag(kbb + (size_t)(m0 + f * 16 + lr) * DQ + lq * 8);

    const unsigned short* qp = qb + ((size_t)b * HW + nc * 512 + lr) * DQ + lq * 8;

    f32x4 acc[8];
    #pragma unroll
    for (int f = 0; f < 8; ++f) acc[f] = (f32x4){0.f, 0.f, 0.f, 0.f};
    f32x4 zz = {0.f, 0.f, 0.f, 0.f};

    for (int i = 0; i < 32; ++i) {
        bf16x8 qf = ldfrag(qp);
        qp += 16 * DQ;
        #pragma unroll
        for (int f = 0; f < 8; ++f) {
            f32x4 s = __builtin_amdgcn_mfma_f32_16x16x32_bf16(af[f], qf, zz, 0, 0, 0);
            acc[f].x += fexp2(s.x); acc[f].y += fexp2(s.y);
            acc[f].z += fexp2(s.z); acc[f].w += fexp2(s.w);
        }
    }
    #pragma unroll
    for (int f = 0; f < 8; ++f) {
        #pragma unroll
        for (int off = 1; off < 16; off <<= 1) {
            acc[f].x += __shfl_xor(acc[f].x, off);
            acc[f].y += __shfl_xor(acc[f].y, off);
            acc[f].z += __shfl_xor(acc[f].z, off);
            acc[f].w += __shfl_xor(acc[f].w, off);
        }
    }
    if (lr == 0) {
        size_t base = (size_t)nc * 32768 + (size_t)b * HW;
        #pragma unroll
        for (int f = 0; f < 8; ++f) {
            size_t p0 = base + m0 + f * 16 + lq * 4;
            zp[p0 + 0] = acc[f].x;
            zp[p0 + 1] = acc[f].y;
            zp[p0 + 2] = acc[f].z;
            zp[p0 + 3] = acc[f].w;
        }
    }
}

// ---------------------------------------------------------------------------
// Kernel 3: zs = gamma/sum(zp); vzc (shuffled f16) so one dwordx4 per lane
// yields two phases of PV A-frags with all bytes used.
// vzc elem index: b*OC*HW + Mb*1024 + o*32 + lq*8 + ph*4 + j,
// holding vz[o][Mb*32 + ph*16 + lq*4 + j].
__global__ __launch_bounds__(256) void k_zvz(const float* __restrict__ zp,
                                             const float* __restrict__ v2,
                                             const float* __restrict__ gamma,
                                             unsigned short* __restrict__ vzc) {
    int i = blockIdx.x * 256 + threadIdx.x;   // 32768 = [b][m]
    float s = 0.f;
    #pragma unroll
    for (int nc = 0; nc < 8; ++nc) s += zp[nc * 32768 + i];
    float zs = gamma[0] / s;
    int b = i >> 12, m = i & 4095;
    int Mb = m >> 5, mloc = m & 31;
    int ph = mloc >> 4, lqm = (mloc >> 2) & 3, j = mloc & 3;
    const float* vsrc = v2 + ((size_t)b * OC) * HW + m;
    unsigned short* dst = vzc + (size_t)b * OC * HW + (size_t)Mb * 1024
                        + lqm * 8 + ph * 4 + j;
    #pragma unroll 8
    for (int o = 0; o < OC; ++o) {
        _Float16 h = (_Float16)(vsrc[(size_t)o * HW] * zs);
        dst[o * 32] = __builtin_bit_cast(unsigned short, h);
    }
}

// ---------------------------------------------------------------------------
// Kernel 4: partial outp[mc][b][o][n] (bf16). Wave owns 128 n (8 tiles):
// every k/v line serves 8 n-tiles. Register-direct f16 PV (K=16) as round 7.
// grid = 1024 x 128 thr: b=bid&7, mc=(bid>>3)&7, ng=bid>>6 (0..15).
__global__ __launch_bounds__(128, 2) void k_attn(
    const unsigned short* __restrict__ qb, const unsigned short* __restrict__ kb,
    const unsigned short* __restrict__ vzc, unsigned short* __restrict__ outp) {
    int t = threadIdx.x;
    int w = t >> 6, l = t & 63;
    int lr = l & 15, lq = l >> 4;
    int bid = blockIdx.x;
    int b = bid & 7, mc = (bid >> 3) & 7, ng = bid >> 6;
    int n0 = ng * 256 + w * 128;

    bf16x8 qf[8];
    #pragma unroll
    for (int tt = 0; tt < 8; ++tt)
        qf[tt] = ldfrag(qb + ((size_t)b * HW + n0 + tt * 16 + lr) * DQ + lq * 8);

    const unsigned short* kp = kb + ((size_t)b * HW + lr) * DQ + lq * 8;
    const unsigned short* vp = vzc + (size_t)b * OC * HW + lr * 32 + lq * 8;

    f32x4 acc0[8], acc1[8];
    #pragma unroll
    for (int tt = 0; tt < 8; ++tt) {
        acc0[tt] = (f32x4){0.f, 0.f, 0.f, 0.f};
        acc1[tt] = (f32x4){0.f, 0.f, 0.f, 0.f};
    }
    f32x4 zz = {0.f, 0.f, 0.f, 0.f};

    int mbeg = mc * 512;
    for (int m0 = mbeg; m0 < mbeg + 512; m0 += 32) {
        int Mb = m0 >> 5;
        uint4 vv0 = *(const uint4*)(vp + (size_t)Mb * 1024);        // o = lr
        uint4 vv1 = *(const uint4*)(vp + (size_t)Mb * 1024 + 512);  // o = lr+16
        #pragma unroll
        for (int ph = 0; ph < 2; ++ph) {
            int mb = m0 + ph * 16;
            bf16x8 a  = ldfrag(kp + (size_t)mb * DQ);
            f16x4 va0 = ph ? u2h4(vv0.z, vv0.w) : u2h4(vv0.x, vv0.y);
            f16x4 va1 = ph ? u2h4(vv1.z, vv1.w) : u2h4(vv1.x, vv1.y);
            #pragma unroll
            for (int tt = 0; tt < 8; ++tt) {
                f32x4 s = __builtin_amdgcn_mfma_f32_16x16x32_bf16(a, qf[tt], zz, 0, 0, 0);
                f16x4 p = pk4(fexp2(s.x), fexp2(s.y), fexp2(s.z), fexp2(s.w));
                acc0[tt] = __builtin_amdgcn_mfma_f32_16x16x16f16(va0, p, acc0[tt], 0, 0, 0);
                acc1[tt] = __builtin_amdgcn_mfma_f32_16x16x16f16(va1, p, acc1[tt], 0, 0, 0);
            }
        }
    }

    // bf16 partial write: C layout col=lr=n, row=lq*4+r=o
    unsigned short* ob = outp + (size_t)(mc * 8 + b) * OC * HW;
    #pragma unroll
    for (int tt = 0; tt < 8; ++tt) {
        int n_t = n0 + tt * 16 + lr;
        #pragma unroll
        for (int r = 0; r < 4; ++r) {
            int o0 = lq * 4 + r;
            ob[(size_t)o0 * HW + n_t]        = (unsigned short)f2bf(acc0[tt][r]);
            ob[(size_t)(o0 + 16) * HW + n_t] = (unsigned short)f2bf(acc1[tt][r]);
        }
    }
}

// ---------------------------------------------------------------------------
// Kernel 5: out = sum_mc bf16 outp[mc] + xs
__global__ __launch_bounds__(256) void k_red(const unsigned short* __restrict__ outp,
                                             const float* __restrict__ xs,
                                             float* __restrict__ out) {
    int i = (blockIdx.x * 256 + threadIdx.x) * 4;
    float4 r = *(const float4*)(xs + i);
    const unsigned short* op = outp + i;
    #pragma unroll
    for (int mc = 0; mc < 8; ++mc) {
        uint2 p = *(const uint2*)(op + (size_t)mc * 1048576);
        r.x += __builtin_bit_cast(float, p.x << 16);
        r.y += __builtin_bit_cast(float, p.x & 0xffff0000u);
        r.z += __builtin_bit_cast(float, p.y << 16);
        r.w += __builtin_bit_cast(float, p.y & 0xffff0000u);
    }
    *(float4*)(out + i) = r;
}

// ---------------------------------------------------------------------------
extern "C" void kernel_launch(void* const* d_in, const int* in_sizes, int n_in,
                              void* d_out, int out_size, void* d_ws, size_t ws_size,
                              hipStream_t stream) {
    const float* x1    = (const float*)d_in[0];
    const float* x2    = (const float*)d_in[1];
    const float* Wq    = (const float*)d_in[2];
    const float* bq    = (const float*)d_in[3];
    const float* Wk    = (const float*)d_in[4];
    const float* bk    = (const float*)d_in[5];
    const float* Wv    = (const float*)d_in[6];
    const float* Wsc   = (const float*)d_in[7];
    const float* gamma = (const float*)d_in[8];
    float* out = (float*)d_out;
    float* ws  = (float*)d_ws;

    float*          wsv  = ws + WSV_OFF;
    unsigned short* qbp  = (unsigned short*)(ws + QB_OFF);
    unsigned short* kbp  = (unsigned short*)(ws + KB_OFF);
    float*          xsp  = ws + XS_OFF;
    float*          v2   = ws + V2_OFF;
    float*          zpp  = ws + ZP_OFF;
    unsigned short* vzc  = (unsigned short*)(ws + VZC_OFF);
    unsigned short* outp = (unsigned short*)(ws + OUTP_OFF);

    k_wcomb<<<8, 256, 0, stream>>>(Wsc, Wv, wsv);
    k_proj<<<512, 256, 0, stream>>>(x1, x2, Wq, bq, Wk, bk, wsv, Wsc,
                                    qbp, kbp, v2, xsp);
    k_stats<<<1024, 128, 0, stream>>>(kbp, qbp, zpp);
    k_zvz<<<128, 256, 0, stream>>>(zpp, v2, gamma, vzc);
    k_attn<<<1024, 128, 0, stream>>>(qbp, kbp, vzc, outp);
    k_red<<<1024, 256, 0, stream>>>(outp, xsp, out);
}